// Round 7
// baseline (369.027 us; speedup 1.0000x reference)
//
#include <hip/hip_runtime.h>
#include <hip/hip_bf16.h>
#include <math.h>

// Problem constants
#define CDIM 256
#define HW   1024          // 32*32
#define NVEC 32768         // B*H*W
#define NE   1024
#define ZSIZE 8388608      // 32*256*32*32
#define NSPLIT 4           // j-splits (256 codes each)
// 1-term fp16 (zh*eh): pairwise-diff sigma ~9e-3 -> 0.12 is ~13 sigma.
// Rescue (exact fp32) absorbs all rows with approx gap < MARGIN.
#define MARGIN 0.12f
// zpack capacity (rows); beyond this rescue falls back to scattered loads.
#define ZPCAP 15360

// Output layout (floats): [loss(1)][z_q(ZSIZE)][perp(1)][idx(NVEC)][z_q1(ZSIZE)]
#define OUT_LOSS 0
#define OUT_ZQ   1
#define OUT_PERP 8388609
#define OUT_IDX  8388610
#define OUT_ZQ1  8421378

// Workspace layout (bytes)
#define WS_LOSS   0         // double (8)
#define WS_RCNT   64
#define WS_GCNT   96
#define WS_MCNT   128       // 256 ints  -> 1152
#define WS_HIST   1152      // 1024 ints -> 5248
#define WS_ENORM  5248      // 1024 f    -> 9344 (pad 9472)
#define WS_IDX    9472      // 32768 ints -> 140544
#define WS_RLIST  140544    // 32768 ints -> 271616
#define WS_S1     271616    // 4*32768 f -> 795904
#define WS_S2     795904    // -> 1320192
#define WS_J1     1320192   // -> 1844480
#define WS_SCORE  1844480   // 32768 u64 -> 2106624
#define WS_EBH    2106624   // 1024*256 fp16 -> 2630912
#define WS_ZBH    2630912   // 32768*256 fp16 -> 19408128
#define WS_ZPACK  19408128  // 15360*256 f32 -> 35136768
#define WS_ZERO_INTS 1312   // bytes 0..5248: loss+rcnt+gcnt+mcnt+hist

typedef __attribute__((ext_vector_type(8))) short short8;
typedef __attribute__((ext_vector_type(4))) float f32x4;
typedef __attribute__((ext_vector_type(8))) unsigned short ushort8v;
typedef __attribute__((ext_vector_type(8))) _Float16 half8;

__device__ __forceinline__ unsigned short f16_rne(float x) {
    _Float16 h = (_Float16)x;
    return __builtin_bit_cast(unsigned short, h);
}
// CK-style block_sync_lds: drains LDS ops + barrier, leaves global loads (vmcnt) in flight.
__device__ __forceinline__ void lds_barrier() {
    asm volatile("s_waitcnt lgkmcnt(0)\n\ts_barrier" ::: "memory");
}

// ---------------- fused prep: z transpose+enc (blocks 0..511), emb enc+norm (512..527)
// Block 512 also zeroes loss/rcnt/gcnt/mcnt/hist.
__global__ __launch_bounds__(256) void vq_prep(
    const float* __restrict__ z, const float* __restrict__ emb,
    unsigned short* __restrict__ zbh, unsigned short* __restrict__ ebh,
    float* __restrict__ enorm, int* __restrict__ wsz)
{
    const int tid = threadIdx.x, w = tid >> 6, L = tid & 63;
    if (blockIdx.x < 512) {
        __shared__ unsigned short th[64 * 264];
        const int b = blockIdx.x >> 4, hw0 = (blockIdx.x & 15) << 6;
        const float* zp = z + (size_t)b * (CDIM * HW) + hw0;
        for (int i = 0; i < 16; ++i) {
            int k = (i * 4 + w) * 4;
            float f0 = zp[(size_t)(k + 0) * HW + L];
            float f1 = zp[(size_t)(k + 1) * HW + L];
            float f2 = zp[(size_t)(k + 2) * HW + L];
            float f3 = zp[(size_t)(k + 3) * HW + L];
            ushort4 hi = { f16_rne(f0), f16_rne(f1), f16_rne(f2), f16_rne(f3) };
            *(ushort4*)&th[L * 264 + k] = hi;
        }
        __syncthreads();
#pragma unroll
        for (int it = 0; it < 8; ++it) {
            int row = it * 8 + (tid >> 5);
            int kc = (tid & 31) * 8;
            size_t o = (size_t)(b * 1024 + hw0 + row) * CDIM + kc;
            *(ushort8v*)(zbh + o) = *(ushort8v*)&th[row * 264 + kc];
        }
    } else {
        if (blockIdx.x == 512) {
            for (int i = tid; i < WS_ZERO_INTS; i += 256) wsz[i] = 0;
        }
        const int cb = (int)(blockIdx.x - 512) * 64;
        for (int p = 0; p < 16; ++p) {
            int code = cb + p * 4 + w;
            float4 v = *(const float4*)(emb + (size_t)code * CDIM + L * 4);
            float s = v.x * v.x + v.y * v.y + v.z * v.z + v.w * v.w;
            for (int off = 32; off; off >>= 1) s += __shfl_down(s, off, 64);
            if (L == 0) enorm[code] = s;
            ushort4 hi = { f16_rne(v.x), f16_rne(v.y), f16_rne(v.z), f16_rne(v.w) };
            *(ushort4*)(ebh + (size_t)code * CDIM + L * 4) = hi;
        }
    }
}

// ---------------- 1-term fp16 MFMA GEMM, panelized + fused merge/zpack ---------
// r6 post-mortem: MFMA floor is ~2us but kernel sat at 45us with MfmaUtil 13% --
// 31 serial barriers with only 8 MFMAs between them. v7: stage a full 64-code x
// K=256 panel (32KB) per barrier PAIR -> 8 barriers total, 64 MFMAs per wave
// between barriers. Fragment layout identical to r6 (verified). Epilogue: the
// last of the 4 js-blocks per mtile (device atomic counter) merges the splits,
// zeroes the scoreboard, appends flagged rows to rlist and packs their z-rows
// (replaces the vq_merge and vq_zpack dispatches; ~15us launch overhead each).
__global__ __launch_bounds__(256, 3) void vq_mfma3(
    const unsigned short* __restrict__ zbh, const unsigned short* __restrict__ ebh,
    const float* __restrict__ enorm, const float* __restrict__ z,
    float* __restrict__ s1_ws, float* __restrict__ s2_ws, int* __restrict__ j1_ws,
    int* __restrict__ idx_ws, float* __restrict__ idx_out, int* __restrict__ hist,
    int* __restrict__ rcnt, int* __restrict__ rlist,
    unsigned long long* __restrict__ score, int* __restrict__ mcnt,
    float* __restrict__ zpack)
{
    __shared__ short bpan[32 * 512];   // 32KB: one 64-code K-panel, seg(jf,kk)
    __shared__ float en_s[256];
    __shared__ int sh_flagn[128];
    __shared__ int sh_flagp[128];
    __shared__ int sh_fcnt, sh_last;

    const int tid = threadIdx.x, w = tid >> 6, L = tid & 63;
    const int l15 = L & 15, q = L >> 4;
    const int r16 = tid & 15, ch = (tid >> 4) & 3;
    const int mtile = blockIdx.x & 255, js = blockIdx.x >> 8;   // js 0..3
    const int n0 = mtile << 7;
    const int jsbase = js << 8;

    // AH (z-high) in regs
    half8 AH[2][8];
#pragma unroll
    for (int mf = 0; mf < 2; ++mf)
#pragma unroll
        for (int kk = 0; kk < 8; ++kk)
            AH[mf][kk] = *(const half8*)(zbh + (size_t)(n0 + w * 32 + mf * 16 + l15) * CDIM + kk * 32 + q * 8);

    en_s[tid] = enorm[jsbase + tid];

    float s1[2][4], s2[2][4]; int j1v[2][4];
#pragma unroll
    for (int mf = 0; mf < 2; ++mf)
#pragma unroll
        for (int r = 0; r < 4; ++r) { s1[mf][r] = -3.4e38f; s2[mf][r] = -3.4e38f; j1v[mf][r] = 0; }

    // wave w stages jf=w of each panel: lane loads code (panel+w*16+r16), k-chunk ch
    const unsigned short* ebase = ebh + (size_t)(jsbase + w * 16 + r16) * CDIM + ch * 8;

    short8 st[8];
#pragma unroll
    for (int kk = 0; kk < 8; ++kk) st[kk] = *(const short8*)(ebase + kk * 32);
#pragma unroll
    for (int kk = 0; kk < 8; ++kk) *(short8*)(bpan + (w * 8 + kk) * 512 + L * 8) = st[kk];
#pragma unroll
    for (int kk = 0; kk < 8; ++kk) st[kk] = *(const short8*)(ebase + 64 * CDIM + kk * 32);
    lds_barrier();

    for (int p = 0; p < 4; ++p) {
        f32x4 acc[2][4] = {};
#pragma unroll
        for (int kk = 0; kk < 8; ++kk) {
#pragma unroll
            for (int jf = 0; jf < 4; ++jf) {
                half8 B = *(const half8*)(bpan + (jf * 8 + kk) * 512 + L * 8);
                acc[0][jf] = __builtin_amdgcn_mfma_f32_16x16x32_f16(AH[0][kk], B, acc[0][jf], 0, 0, 0);
                acc[1][jf] = __builtin_amdgcn_mfma_f32_16x16x32_f16(AH[1][kk], B, acc[1][jf], 0, 0, 0);
            }
        }
        // fold scores for this panel's 64 codes
#pragma unroll
        for (int jf = 0; jf < 4; ++jf) {
            const int jl = p * 64 + jf * 16 + l15;
            const int j = jsbase + jl;
            const float hn = 0.5f * en_s[jl];
#pragma unroll
            for (int mf = 0; mf < 2; ++mf)
#pragma unroll
                for (int r = 0; r < 4; ++r) {
                    float s = acc[mf][jf][r] - hn;
                    if (s > s1[mf][r]) { s2[mf][r] = s1[mf][r]; s1[mf][r] = s; j1v[mf][r] = j; }
                    else if (s > s2[mf][r]) s2[mf][r] = s;
                }
        }
        if (p < 3) {
            lds_barrier();   // all reads of bpan done
#pragma unroll
            for (int kk = 0; kk < 8; ++kk) *(short8*)(bpan + (w * 8 + kk) * 512 + L * 8) = st[kk];
            if (p < 2) {
#pragma unroll
                for (int kk = 0; kk < 8; ++kk)
                    st[kk] = *(const short8*)(ebase + (size_t)(p + 2) * 64 * CDIM + kk * 32);
            }
            lds_barrier();   // writes visible
        }
    }

    // per-row (16-lane) reduce, write split results
#pragma unroll
    for (int mf = 0; mf < 2; ++mf)
#pragma unroll
        for (int r = 0; r < 4; ++r) {
            float a1 = s1[mf][r], a2 = s2[mf][r]; int aj = j1v[mf][r];
            for (int m = 1; m < 16; m <<= 1) {
                float o1 = __shfl_xor(a1, m, 64);
                float o2 = __shfl_xor(a2, m, 64);
                int   oj = __shfl_xor(aj, m, 64);
                if (o1 > a1 || (o1 == a1 && oj < aj)) { a2 = fmaxf(a1, o2); a1 = o1; aj = oj; }
                else a2 = fmaxf(a2, o1);
            }
            if (l15 == 0) {
                int o = js * NVEC + n0 + w * 32 + mf * 16 + q * 4 + r;
                s1_ws[o] = a1; s2_ws[o] = a2; j1_ws[o] = aj;
            }
        }

    // -------- fused merge + zpack: last js-block for this mtile --------
    if (tid == 0) sh_fcnt = 0;
    __syncthreads();                    // drains each wave's stores (vmcnt 0)
    if (tid == 0) {
        __threadfence();                // release our split's stores device-wide
        sh_last = (atomicAdd(&mcnt[mtile], 1) == NSPLIT - 1);
    }
    __syncthreads();
    if (!sh_last) return;

    if (tid < 128) {
        const int n = n0 + tid;
        float b1 = -3.4e38f, b2 = -3.4e38f; int bj = 0;
#pragma unroll
        for (int s = 0; s < NSPLIT; ++s) {
            float a1 = s1_ws[s * NVEC + n], a2 = s2_ws[s * NVEC + n];
            int aj = j1_ws[s * NVEC + n];
            if (a1 > b1 || (a1 == b1 && aj < bj)) { b2 = fmaxf(b1, a2); b1 = a1; bj = aj; }
            else b2 = fmaxf(b2, a1);
        }
        score[n] = 0ull;
        if (b1 - b2 < MARGIN) {
            idx_ws[n] = -1;
            int pos = atomicAdd(rcnt, 1); rlist[pos] = n;
            int c = atomicAdd(&sh_fcnt, 1); sh_flagn[c] = n; sh_flagp[c] = pos;
        } else {
            idx_ws[n] = bj;
            idx_out[n] = (float)bj;
            atomicAdd(&hist[bj], 1);
        }
    }
    __syncthreads();
    const int fc = sh_fcnt;
    for (int i = 0; i < fc; ++i) {
        const int n = sh_flagn[i], pos = sh_flagp[i];
        if (pos < ZPCAP)
            zpack[(size_t)pos * 256 + tid] =
                z[(size_t)(n >> 10) * (CDIM * HW) + (size_t)tid * HW + (n & 1023)];
    }
}

// ---------------- exact fp32 rescore of flagged rows ---------------------------
// 16 blocks per row, 64 codes per block, 16 per wave -> 8 dual-code iterations.
// z row comes from the packed buffer (coalesced float4), emb from L2.
// Partial (score,j) merges via per-ROW packed u64 atomicMax scoreboard.
__global__ __launch_bounds__(256) void vq_rescue(
    const float* __restrict__ z, const float* __restrict__ emb,
    const float* __restrict__ enorm, const int* __restrict__ rcnt,
    const int* __restrict__ rlist, const float* __restrict__ zpack,
    unsigned long long* __restrict__ score)
{
    __shared__ float en_s[64];
    __shared__ __align__(16) float zrow[256];
    __shared__ float rs[4];
    __shared__ int   rj[4];
    const int tid = threadIdx.x;
    const int wv = tid >> 6, L = tid & 63;
    const int chunk = blockIdx.x & 15;        // 16 chunks of 64 codes
    const int jwave = chunk * 64 + wv * 16;   // this wave's 16 codes
    const int jodd = L >> 5;                  // lo half-wave: even code, hi: odd
    const int rstride = gridDim.x >> 4;
    const int count = *rcnt;

    if (tid < 64) en_s[tid] = enorm[chunk * 64 + tid];
    __syncthreads();

    for (int it = blockIdx.x >> 4; it < count; it += rstride) {
        const int n = rlist[it];
        float4 zv;
        if (it < ZPCAP) {
            zv = *(const float4*)(zpack + (size_t)it * 256 + L * 4);
        } else {
            __syncthreads();
            zrow[tid] = z[(size_t)(n >> 10) * (CDIM * HW) + (size_t)tid * HW + (n & 1023)];
            __syncthreads();
            zv = *(const float4*)&zrow[L * 4];
        }

        float b1 = -3.4e38f; int bj = 0x7fffffff;
#pragma unroll
        for (int jo = 0; jo < 16; jo += 2) {
            const int jA = jwave + jo;
            const float4 eA = *(const float4*)(emb + (size_t)jA * CDIM + L * 4);
            const float4 eB = *(const float4*)(emb + (size_t)(jA + 1) * CDIM + L * 4);
            float pA = fmaf(zv.x, eA.x, fmaf(zv.y, eA.y, fmaf(zv.z, eA.z, zv.w * eA.w)));
            float pB = fmaf(zv.x, eB.x, fmaf(zv.y, eB.y, fmaf(zv.z, eB.z, zv.w * eB.w)));
            // dual reduce: fold opposite halves, then 5-step butterfly.
            float tA = pA + __shfl_xor(pA, 32, 64);
            float tB = pB + __shfl_xor(pB, 32, 64);
            float u = (L < 32) ? tA : tB;
            u += __shfl_xor(u, 16, 64);
            u += __shfl_xor(u, 8, 64);
            u += __shfl_xor(u, 4, 64);
            u += __shfl_xor(u, 2, 64);
            u += __shfl_xor(u, 1, 64);
            const int j = jA + jodd;
            const float s = u - 0.5f * en_s[wv * 16 + jo + jodd];
            // ascending j within each half-stream: strict > keeps smallest j
            if (s > b1) { b1 = s; bj = j; }
        }
        // merge the two half-wave streams (even vs odd codes)
        {
            const float o1 = __shfl_xor(b1, 32, 64);
            const int   oj = __shfl_xor(bj, 32, 64);
            if (o1 > b1 || (o1 == b1 && oj < bj)) { b1 = o1; bj = oj; }
        }
        __syncthreads();   // protect rs/rj reuse across iterations
        if (L == 0) { rs[wv] = b1; rj[wv] = bj; }
        __syncthreads();
        if (tid == 0) {
            float f1 = rs[0]; int fj = rj[0];
#pragma unroll
            for (int v = 1; v < 4; ++v)
                if (rs[v] > f1 || (rs[v] == f1 && rj[v] < fj)) { f1 = rs[v]; fj = rj[v]; }
            unsigned key = __float_as_uint(f1);
            key = (key & 0x80000000u) ? ~key : (key | 0x80000000u);
            unsigned long long packed = ((unsigned long long)key << 32) | (unsigned)(~fj);
            atomicMax(&score[n], packed);
        }
    }
}

// ---------------- gather + outputs + loss + fused finalize ---------------------
__global__ __launch_bounds__(256) void vq_gather(
    const float* __restrict__ z, const float* __restrict__ emb,
    const int* __restrict__ idx_ws, const unsigned long long* __restrict__ score,
    float* __restrict__ zq, float* __restrict__ zq1,
    float* __restrict__ idx_out, int* __restrict__ hist,
    double* __restrict__ loss_sum, int* __restrict__ gcnt,
    float* __restrict__ out_loss, float* __restrict__ out_perp)
{
    __shared__ float es[32 * 129];
    __shared__ int ids[32];
    __shared__ float wred[4];
    __shared__ int sh_last;

    const int tid = threadIdx.x, w = tid >> 6, L = tid & 63;
    const int b   = blockIdx.x >> 6;
    const int half = (blockIdx.x >> 5) & 1;
    const int hw0 = (blockIdx.x & 31) << 5;
    const int n0  = (b << 10) + hw0;
    const int c0  = half << 7;

    if (tid < 32) {
        const int n = n0 + tid;
        int id = idx_ws[n];
        if (id < 0) {
            id = (int)(~(unsigned)score[n]) & (NE - 1);
            if (half == 0) {            // exactly-once fixup for flagged rows
                idx_out[n] = (float)id;
                atomicAdd(&hist[id], 1);
            }
        }
        ids[tid] = id;
    }
    __syncthreads();

#pragma unroll
    for (int p = 0; p < 4; ++p) {
        int u = p * 256 + tid;
        int r = u >> 5, cq = (u & 31) * 4;
        float4 v = *(const float4*)(emb + (size_t)ids[r] * CDIM + c0 + cq);
        es[r * 129 + cq + 0] = v.x;
        es[r * 129 + cq + 1] = v.y;
        es[r * 129 + cq + 2] = v.z;
        es[r * 129 + cq + 3] = v.w;
    }
    __syncthreads();

    const int row = L & 31, cp = L >> 5;
    const size_t zbase = (size_t)b * (CDIM * HW) + hw0 + row;
    float ls = 0.f;
    for (int rd = 0; rd < 16; ++rd) {
        int cl = rd * 8 + w * 2 + cp;
        size_t off = zbase + (size_t)(c0 + cl) * HW;
        float zv = z[off];
        float e  = es[row * 129 + cl];
        float d  = e - zv;
        zq[off]  = zv + d;     // match ref: zp + (z_q1 - zp)
        zq1[off] = e;
        ls += d * d;
    }

    for (int off = 32; off; off >>= 1) ls += __shfl_down(ls, off, 64);
    if (L == 0) wred[w] = ls;
    __syncthreads();
    if (tid == 0)
        atomicAdd(loss_sum, (double)(wred[0] + wred[1] + wred[2] + wred[3]));

    // -------- fused finalize: last block computes loss scalar + perplexity -----
    __syncthreads();
    if (tid == 0) {
        __threadfence();
        sh_last = (atomicAdd(gcnt, 1) == (int)gridDim.x - 1);
    }
    __syncthreads();
    if (!sh_last) return;

    float term = 0.f;
    for (int i = tid; i < NE; i += 256) {
        float em = (float)atomicAdd(&hist[i], 0) * (1.0f / 32768.0f);
        term += em * logf(em + 1e-10f);
    }
    for (int off = 32; off; off >>= 1) term += __shfl_down(term, off, 64);
    if (L == 0) wred[w] = term;
    __syncthreads();
    if (tid == 0) {
        double lsum = atomicAdd(loss_sum, 0.0);
        *out_perp = expf(-(wred[0] + wred[1] + wred[2] + wred[3]));
        *out_loss = (float)(lsum * 1.25 / 8388608.0);
    }
}

extern "C" void kernel_launch(void* const* d_in, const int* in_sizes, int n_in,
                              void* d_out, int out_size, void* d_ws, size_t ws_size,
                              hipStream_t stream) {
    const float* z   = (const float*)d_in[0];
    const float* emb = (const float*)d_in[1];
    float* out = (float*)d_out;
    char*  ws  = (char*)d_ws;

    double* loss_sum    = (double*)(ws + WS_LOSS);
    int*    rcnt        = (int*)(ws + WS_RCNT);
    int*    gcnt        = (int*)(ws + WS_GCNT);
    int*    mcnt        = (int*)(ws + WS_MCNT);
    int*    hist        = (int*)(ws + WS_HIST);
    float*  enorm       = (float*)(ws + WS_ENORM);
    int*    idx_ws      = (int*)(ws + WS_IDX);
    int*    rlist       = (int*)(ws + WS_RLIST);
    float*  s1_ws       = (float*)(ws + WS_S1);
    float*  s2_ws       = (float*)(ws + WS_S2);
    int*    j1_ws       = (int*)(ws + WS_J1);
    unsigned short* ebh = (unsigned short*)(ws + WS_EBH);
    unsigned short* zbh = (unsigned short*)(ws + WS_ZBH);
    float*  zpack       = (float*)(ws + WS_ZPACK);
    unsigned long long* score = (unsigned long long*)(ws + WS_SCORE);

    vq_prep  <<<528, 256, 0, stream>>>(z, emb, zbh, ebh, enorm, (int*)ws);
    vq_mfma3 <<<1024, 256, 0, stream>>>(zbh, ebh, enorm, z, s1_ws, s2_ws, j1_ws,
                                        idx_ws, out + OUT_IDX, hist, rcnt, rlist,
                                        score, mcnt, zpack);
    vq_rescue<<<2048, 256, 0, stream>>>(z, emb, enorm, rcnt, rlist, zpack, score);
    vq_gather<<<2048, 256, 0, stream>>>(z, emb, idx_ws, score, out + OUT_ZQ, out + OUT_ZQ1,
                                        out + OUT_IDX, hist, loss_sum, gcnt,
                                        out + OUT_LOSS, out + OUT_PERP);
}

// Round 8
// 233.359 us; speedup vs baseline: 1.5814x; 1.5814x over previous
//
#include <hip/hip_runtime.h>
#include <hip/hip_bf16.h>
#include <math.h>

// Problem constants
#define CDIM 256
#define HW   1024          // 32*32
#define NVEC 32768         // B*H*W
#define NE   1024
#define ZSIZE 8388608      // 32*256*32*32
#define NSPLIT 4           // j-splits (256 codes each)
// 1-term fp16 (zh*eh): pairwise-diff sigma ~9e-3 -> 0.12 is ~13 sigma.
#define MARGIN 0.12f
#define ZPCAP 15360

// Output layout (floats): [loss(1)][z_q(ZSIZE)][perp(1)][idx(NVEC)][z_q1(ZSIZE)]
#define OUT_LOSS 0
#define OUT_ZQ   1
#define OUT_PERP 8388609
#define OUT_IDX  8388610
#define OUT_ZQ1  8421378

// Workspace layout (bytes)
#define WS_LOSS   0         // (unused legacy)
#define WS_RCNT   64
#define WS_GCNT   96
#define WS_MCNT   128       // 256 ints  -> 1152
#define WS_HIST   1152      // 1024 ints -> 5248
#define WS_ENORM  5248      // 1024 f    -> 9344 (pad 9472)
#define WS_IDX    9472      // 32768 ints -> 140544
#define WS_RLIST  140544    // 32768 ints -> 271616
#define WS_S1     271616    // 4*32768 f -> 795904
#define WS_S2     795904    // -> 1320192
#define WS_J1     1320192   // -> 1844480
#define WS_SCORE  1844480   // 32768 u64 -> 2106624
#define WS_EBH    2106624   // 1024*256 fp16 -> 2630912
#define WS_ZBH    2630912   // 32768*256 fp16 -> 19408128
#define WS_ZPACK  19408128  // 15360*256 f32 -> 35136768
#define WS_LPART  35136768  // 2048 f32 -> 35144960
#define WS_ZERO_INTS 1312   // bytes 0..5248: loss+rcnt+gcnt+mcnt+hist

typedef __attribute__((ext_vector_type(8))) short short8;
typedef __attribute__((ext_vector_type(4))) float f32x4;
typedef __attribute__((ext_vector_type(8))) unsigned short ushort8v;
typedef __attribute__((ext_vector_type(8))) _Float16 half8;

__device__ __forceinline__ unsigned short f16_rne(float x) {
    _Float16 h = (_Float16)x;
    return __builtin_bit_cast(unsigned short, h);
}
// CK-style block_sync_lds: drains LDS ops + barrier, leaves global loads (vmcnt) in flight.
__device__ __forceinline__ void lds_barrier() {
    asm volatile("s_waitcnt lgkmcnt(0)\n\ts_barrier" ::: "memory");
}

// ---------------- fused prep: z transpose+enc (blocks 0..511), emb enc+norm (512..527)
// Block 512 also zeroes loss/rcnt/gcnt/mcnt/hist.
__global__ __launch_bounds__(256) void vq_prep(
    const float* __restrict__ z, const float* __restrict__ emb,
    unsigned short* __restrict__ zbh, unsigned short* __restrict__ ebh,
    float* __restrict__ enorm, int* __restrict__ wsz)
{
    const int tid = threadIdx.x, w = tid >> 6, L = tid & 63;
    if (blockIdx.x < 512) {
        __shared__ unsigned short th[64 * 264];
        const int b = blockIdx.x >> 4, hw0 = (blockIdx.x & 15) << 6;
        const float* zp = z + (size_t)b * (CDIM * HW) + hw0;
        for (int i = 0; i < 16; ++i) {
            int k = (i * 4 + w) * 4;
            float f0 = zp[(size_t)(k + 0) * HW + L];
            float f1 = zp[(size_t)(k + 1) * HW + L];
            float f2 = zp[(size_t)(k + 2) * HW + L];
            float f3 = zp[(size_t)(k + 3) * HW + L];
            ushort4 hi = { f16_rne(f0), f16_rne(f1), f16_rne(f2), f16_rne(f3) };
            *(ushort4*)&th[L * 264 + k] = hi;
        }
        __syncthreads();
#pragma unroll
        for (int it = 0; it < 8; ++it) {
            int row = it * 8 + (tid >> 5);
            int kc = (tid & 31) * 8;
            size_t o = (size_t)(b * 1024 + hw0 + row) * CDIM + kc;
            *(ushort8v*)(zbh + o) = *(ushort8v*)&th[row * 264 + kc];
        }
    } else {
        if (blockIdx.x == 512) {
            for (int i = tid; i < WS_ZERO_INTS; i += 256) wsz[i] = 0;
        }
        const int cb = (int)(blockIdx.x - 512) * 64;
        for (int p = 0; p < 16; ++p) {
            int code = cb + p * 4 + w;
            float4 v = *(const float4*)(emb + (size_t)code * CDIM + L * 4);
            float s = v.x * v.x + v.y * v.y + v.z * v.z + v.w * v.w;
            for (int off = 32; off; off >>= 1) s += __shfl_down(s, off, 64);
            if (L == 0) enorm[code] = s;
            ushort4 hi = { f16_rne(v.x), f16_rne(v.y), f16_rne(v.z), f16_rne(v.w) };
            *(ushort4*)(ebh + (size_t)code * CDIM + L * 4) = hi;
        }
    }
}

// ---------------- 1-term fp16 MFMA GEMM, panelized (8 barriers total) ----------
// 64-code x K=256 panel (32KB) per barrier pair; 64 MFMAs/wave between barriers.
// No fused epilogue (r7 post-mortem: per-block __threadfence poisoned L2).
__global__ __launch_bounds__(256, 3) void vq_mfma3(
    const unsigned short* __restrict__ zbh, const unsigned short* __restrict__ ebh,
    const float* __restrict__ enorm,
    float* __restrict__ s1_ws, float* __restrict__ s2_ws, int* __restrict__ j1_ws)
{
    __shared__ short bpan[32 * 512];   // 32KB: one 64-code K-panel, seg(jf,kk)
    __shared__ float en_s[256];

    const int tid = threadIdx.x, w = tid >> 6, L = tid & 63;
    const int l15 = L & 15, q = L >> 4;
    const int r16 = tid & 15, ch = (tid >> 4) & 3;
    const int mtile = blockIdx.x & 255, js = blockIdx.x >> 8;   // js 0..3
    const int n0 = mtile << 7;
    const int jsbase = js << 8;

    // AH (z-high) in regs
    half8 AH[2][8];
#pragma unroll
    for (int mf = 0; mf < 2; ++mf)
#pragma unroll
        for (int kk = 0; kk < 8; ++kk)
            AH[mf][kk] = *(const half8*)(zbh + (size_t)(n0 + w * 32 + mf * 16 + l15) * CDIM + kk * 32 + q * 8);

    en_s[tid] = enorm[jsbase + tid];

    float s1[2][4], s2[2][4]; int j1v[2][4];
#pragma unroll
    for (int mf = 0; mf < 2; ++mf)
#pragma unroll
        for (int r = 0; r < 4; ++r) { s1[mf][r] = -3.4e38f; s2[mf][r] = -3.4e38f; j1v[mf][r] = 0; }

    // wave w stages jf=w of each panel
    const unsigned short* ebase = ebh + (size_t)(jsbase + w * 16 + r16) * CDIM + ch * 8;

    short8 st[8];
#pragma unroll
    for (int kk = 0; kk < 8; ++kk) st[kk] = *(const short8*)(ebase + kk * 32);
#pragma unroll
    for (int kk = 0; kk < 8; ++kk) *(short8*)(bpan + (w * 8 + kk) * 512 + L * 8) = st[kk];
#pragma unroll
    for (int kk = 0; kk < 8; ++kk) st[kk] = *(const short8*)(ebase + 64 * CDIM + kk * 32);
    lds_barrier();

    for (int p = 0; p < 4; ++p) {
        f32x4 acc[2][4] = {};
#pragma unroll
        for (int kk = 0; kk < 8; ++kk) {
#pragma unroll
            for (int jf = 0; jf < 4; ++jf) {
                half8 B = *(const half8*)(bpan + (jf * 8 + kk) * 512 + L * 8);
                acc[0][jf] = __builtin_amdgcn_mfma_f32_16x16x32_f16(AH[0][kk], B, acc[0][jf], 0, 0, 0);
                acc[1][jf] = __builtin_amdgcn_mfma_f32_16x16x32_f16(AH[1][kk], B, acc[1][jf], 0, 0, 0);
            }
        }
#pragma unroll
        for (int jf = 0; jf < 4; ++jf) {
            const int jl = p * 64 + jf * 16 + l15;
            const int j = jsbase + jl;
            const float hn = 0.5f * en_s[jl];
#pragma unroll
            for (int mf = 0; mf < 2; ++mf)
#pragma unroll
                for (int r = 0; r < 4; ++r) {
                    float s = acc[mf][jf][r] - hn;
                    if (s > s1[mf][r]) { s2[mf][r] = s1[mf][r]; s1[mf][r] = s; j1v[mf][r] = j; }
                    else if (s > s2[mf][r]) s2[mf][r] = s;
                }
        }
        if (p < 3) {
            lds_barrier();   // all reads of bpan done
#pragma unroll
            for (int kk = 0; kk < 8; ++kk) *(short8*)(bpan + (w * 8 + kk) * 512 + L * 8) = st[kk];
            if (p < 2) {
#pragma unroll
                for (int kk = 0; kk < 8; ++kk)
                    st[kk] = *(const short8*)(ebase + (size_t)(p + 2) * 64 * CDIM + kk * 32);
            }
            lds_barrier();   // writes visible
        }
    }

#pragma unroll
    for (int mf = 0; mf < 2; ++mf)
#pragma unroll
        for (int r = 0; r < 4; ++r) {
            float a1 = s1[mf][r], a2 = s2[mf][r]; int aj = j1v[mf][r];
            for (int m = 1; m < 16; m <<= 1) {
                float o1 = __shfl_xor(a1, m, 64);
                float o2 = __shfl_xor(a2, m, 64);
                int   oj = __shfl_xor(aj, m, 64);
                if (o1 > a1 || (o1 == a1 && oj < aj)) { a2 = fmaxf(a1, o2); a1 = o1; aj = oj; }
                else a2 = fmaxf(a2, o1);
            }
            if (l15 == 0) {
                int o = js * NVEC + n0 + w * 32 + mf * 16 + q * 4 + r;
                s1_ws[o] = a1; s2_ws[o] = a2; j1_ws[o] = aj;
            }
        }
}

// ---------------- merge 4 splits; confident rows -> outputs; rest -> rlist ----
__global__ __launch_bounds__(256) void vq_merge(
    const float* __restrict__ s1_ws, const float* __restrict__ s2_ws,
    const int* __restrict__ j1_ws, int* __restrict__ idx_ws,
    float* __restrict__ idx_out, int* __restrict__ hist,
    int* __restrict__ rcnt, int* __restrict__ rlist,
    unsigned long long* __restrict__ score)
{
    int n = blockIdx.x * 256 + threadIdx.x;
    score[n] = 0ull;
    float b1 = -3.4e38f, b2 = -3.4e38f; int bj = 0;
#pragma unroll
    for (int s = 0; s < NSPLIT; ++s) {
        float a1 = s1_ws[s * NVEC + n], a2 = s2_ws[s * NVEC + n];
        int aj = j1_ws[s * NVEC + n];
        if (a1 > b1 || (a1 == b1 && aj < bj)) { b2 = fmaxf(b1, a2); b1 = a1; bj = aj; }
        else b2 = fmaxf(b2, a1);
    }
    if (b1 - b2 < MARGIN) {
        idx_ws[n] = -1;
        int p = atomicAdd(rcnt, 1); rlist[p] = n;
    } else {
        idx_ws[n] = bj;
        idx_out[n] = (float)bj;
        atomicAdd(&hist[bj], 1);
    }
}

// ---------------- pack flagged z rows once -------------------------------------
__global__ __launch_bounds__(256) void vq_zpack(
    const float* __restrict__ z, const int* __restrict__ rcnt,
    const int* __restrict__ rlist, float* __restrict__ zpack)
{
    const int count = min(*rcnt, ZPCAP);
    for (int it = blockIdx.x; it < count; it += gridDim.x) {
        const int n = rlist[it];
        zpack[(size_t)it * 256 + threadIdx.x] =
            z[(size_t)(n >> 10) * (CDIM * HW) + (size_t)threadIdx.x * HW + (n & 1023)];
    }
}

// ---------------- exact fp32 rescore of flagged rows ---------------------------
__global__ __launch_bounds__(256) void vq_rescue(
    const float* __restrict__ z, const float* __restrict__ emb,
    const float* __restrict__ enorm, const int* __restrict__ rcnt,
    const int* __restrict__ rlist, const float* __restrict__ zpack,
    unsigned long long* __restrict__ score)
{
    __shared__ float en_s[64];
    __shared__ __align__(16) float zrow[256];
    __shared__ float rs[4];
    __shared__ int   rj[4];
    const int tid = threadIdx.x;
    const int wv = tid >> 6, L = tid & 63;
    const int chunk = blockIdx.x & 15;        // 16 chunks of 64 codes
    const int jwave = chunk * 64 + wv * 16;   // this wave's 16 codes
    const int jodd = L >> 5;                  // lo half-wave: even code, hi: odd
    const int rstride = gridDim.x >> 4;
    const int count = *rcnt;

    if (tid < 64) en_s[tid] = enorm[chunk * 64 + tid];
    __syncthreads();

    for (int it = blockIdx.x >> 4; it < count; it += rstride) {
        const int n = rlist[it];
        float4 zv;
        if (it < ZPCAP) {
            zv = *(const float4*)(zpack + (size_t)it * 256 + L * 4);
        } else {
            __syncthreads();
            zrow[tid] = z[(size_t)(n >> 10) * (CDIM * HW) + (size_t)tid * HW + (n & 1023)];
            __syncthreads();
            zv = *(const float4*)&zrow[L * 4];
        }

        float b1 = -3.4e38f; int bj = 0x7fffffff;
#pragma unroll
        for (int jo = 0; jo < 16; jo += 2) {
            const int jA = jwave + jo;
            const float4 eA = *(const float4*)(emb + (size_t)jA * CDIM + L * 4);
            const float4 eB = *(const float4*)(emb + (size_t)(jA + 1) * CDIM + L * 4);
            float pA = fmaf(zv.x, eA.x, fmaf(zv.y, eA.y, fmaf(zv.z, eA.z, zv.w * eA.w)));
            float pB = fmaf(zv.x, eB.x, fmaf(zv.y, eB.y, fmaf(zv.z, eB.z, zv.w * eB.w)));
            float tA = pA + __shfl_xor(pA, 32, 64);
            float tB = pB + __shfl_xor(pB, 32, 64);
            float u = (L < 32) ? tA : tB;
            u += __shfl_xor(u, 16, 64);
            u += __shfl_xor(u, 8, 64);
            u += __shfl_xor(u, 4, 64);
            u += __shfl_xor(u, 2, 64);
            u += __shfl_xor(u, 1, 64);
            const int j = jA + jodd;
            const float s = u - 0.5f * en_s[wv * 16 + jo + jodd];
            if (s > b1) { b1 = s; bj = j; }
        }
        {
            const float o1 = __shfl_xor(b1, 32, 64);
            const int   oj = __shfl_xor(bj, 32, 64);
            if (o1 > b1 || (o1 == b1 && oj < bj)) { b1 = o1; bj = oj; }
        }
        __syncthreads();
        if (L == 0) { rs[wv] = b1; rj[wv] = bj; }
        __syncthreads();
        if (tid == 0) {
            float f1 = rs[0]; int fj = rj[0];
#pragma unroll
            for (int v = 1; v < 4; ++v)
                if (rs[v] > f1 || (rs[v] == f1 && rj[v] < fj)) { f1 = rs[v]; fj = rj[v]; }
            unsigned key = __float_as_uint(f1);
            key = (key & 0x80000000u) ? ~key : (key | 0x80000000u);
            unsigned long long packed = ((unsigned long long)key << 32) | (unsigned)(~fj);
            atomicMax(&score[n], packed);
        }
    }
}

// ---------------- gather + outputs + per-block loss partial --------------------
// r7 post-mortem: the per-block atomicAdd(double*) on ONE address (CAS loop,
// line ping-pong across 8 XCDs) serialized 2048 blocks -> gather was ~120-158us
// at VALUBusy 2%. Now each block stores its partial; vq_final reduces.
__global__ __launch_bounds__(256) void vq_gather(
    const float* __restrict__ z, const float* __restrict__ emb,
    const int* __restrict__ idx_ws, const unsigned long long* __restrict__ score,
    float* __restrict__ zq, float* __restrict__ zq1,
    float* __restrict__ idx_out, int* __restrict__ hist,
    float* __restrict__ loss_part)
{
    __shared__ float es[32 * 129];
    __shared__ int ids[32];
    __shared__ float wred[4];

    const int tid = threadIdx.x, w = tid >> 6, L = tid & 63;
    const int b   = blockIdx.x >> 6;
    const int half = (blockIdx.x >> 5) & 1;
    const int hw0 = (blockIdx.x & 31) << 5;
    const int n0  = (b << 10) + hw0;
    const int c0  = half << 7;

    if (tid < 32) {
        const int n = n0 + tid;
        int id = idx_ws[n];
        if (id < 0) {
            id = (int)(~(unsigned)score[n]) & (NE - 1);
            if (half == 0) {            // exactly-once fixup for flagged rows
                idx_out[n] = (float)id;
                atomicAdd(&hist[id], 1);
            }
        }
        ids[tid] = id;
    }
    __syncthreads();

#pragma unroll
    for (int p = 0; p < 4; ++p) {
        int u = p * 256 + tid;
        int r = u >> 5, cq = (u & 31) * 4;
        float4 v = *(const float4*)(emb + (size_t)ids[r] * CDIM + c0 + cq);
        es[r * 129 + cq + 0] = v.x;
        es[r * 129 + cq + 1] = v.y;
        es[r * 129 + cq + 2] = v.z;
        es[r * 129 + cq + 3] = v.w;
    }
    __syncthreads();

    const int row = L & 31, cp = L >> 5;
    const size_t zbase = (size_t)b * (CDIM * HW) + hw0 + row;
    float ls = 0.f;
    for (int rd = 0; rd < 16; ++rd) {
        int cl = rd * 8 + w * 2 + cp;
        size_t off = zbase + (size_t)(c0 + cl) * HW;
        float zv = z[off];
        float e  = es[row * 129 + cl];
        float d  = e - zv;
        zq[off]  = zv + d;     // match ref: zp + (z_q1 - zp)
        zq1[off] = e;
        ls += d * d;
    }

    for (int off = 32; off; off >>= 1) ls += __shfl_down(ls, off, 64);
    if (L == 0) wred[w] = ls;
    __syncthreads();
    if (tid == 0)
        loss_part[blockIdx.x] = wred[0] + wred[1] + wred[2] + wred[3];
}

// ---------------- finalize: loss scalar + perplexity ---------------------------
__global__ __launch_bounds__(1024) void vq_final(
    const int* __restrict__ hist, const float* __restrict__ loss_part,
    float* __restrict__ out_loss, float* __restrict__ out_perp)
{
    int tid = threadIdx.x;
    float em = (float)hist[tid] * (1.0f / 32768.0f);
    float term = em * logf(em + 1e-10f);
    double dl = (double)loss_part[tid] + (double)loss_part[tid + 1024];
    for (int off = 32; off; off >>= 1) {
        term += __shfl_down(term, off, 64);
        dl   += __shfl_down(dl, off, 64);
    }
    __shared__ float red[16];
    __shared__ double redd[16];
    int lane = tid & 63, wv = tid >> 6;
    if (lane == 0) { red[wv] = term; redd[wv] = dl; }
    __syncthreads();
    if (tid == 0) {
        float s = 0.f; double dsum = 0.0;
        for (int i = 0; i < 16; ++i) { s += red[i]; dsum += redd[i]; }
        *out_perp = expf(-s);
        *out_loss = (float)(dsum * 1.25 / 8388608.0);
    }
}

extern "C" void kernel_launch(void* const* d_in, const int* in_sizes, int n_in,
                              void* d_out, int out_size, void* d_ws, size_t ws_size,
                              hipStream_t stream) {
    const float* z   = (const float*)d_in[0];
    const float* emb = (const float*)d_in[1];
    float* out = (float*)d_out;
    char*  ws  = (char*)d_ws;

    int*    rcnt        = (int*)(ws + WS_RCNT);
    int*    hist        = (int*)(ws + WS_HIST);
    float*  enorm       = (float*)(ws + WS_ENORM);
    int*    idx_ws      = (int*)(ws + WS_IDX);
    int*    rlist       = (int*)(ws + WS_RLIST);
    float*  s1_ws       = (float*)(ws + WS_S1);
    float*  s2_ws       = (float*)(ws + WS_S2);
    int*    j1_ws       = (int*)(ws + WS_J1);
    unsigned short* ebh = (unsigned short*)(ws + WS_EBH);
    unsigned short* zbh = (unsigned short*)(ws + WS_ZBH);
    float*  zpack       = (float*)(ws + WS_ZPACK);
    float*  loss_part   = (float*)(ws + WS_LPART);
    unsigned long long* score = (unsigned long long*)(ws + WS_SCORE);

    vq_prep  <<<528, 256, 0, stream>>>(z, emb, zbh, ebh, enorm, (int*)ws);
    vq_mfma3 <<<1024, 256, 0, stream>>>(zbh, ebh, enorm, s1_ws, s2_ws, j1_ws);
    vq_merge <<<128, 256, 0, stream>>>(s1_ws, s2_ws, j1_ws, idx_ws, out + OUT_IDX, hist, rcnt, rlist, score);
    vq_zpack <<<1024, 256, 0, stream>>>(z, rcnt, rlist, zpack);
    vq_rescue<<<2048, 256, 0, stream>>>(z, emb, enorm, rcnt, rlist, zpack, score);
    vq_gather<<<2048, 256, 0, stream>>>(z, emb, idx_ws, score, out + OUT_ZQ, out + OUT_ZQ1,
                                        out + OUT_IDX, hist, loss_part);
    vq_final <<<1, 1024, 0, stream>>>(hist, loss_part, out + OUT_LOSS, out + OUT_PERP);
}

// Round 9
// 229.586 us; speedup vs baseline: 1.6074x; 1.0164x over previous
//
#include <hip/hip_runtime.h>
#include <hip/hip_bf16.h>
#include <math.h>

// Problem constants
#define CDIM 256
#define HW   1024          // 32*32
#define NVEC 32768         // B*H*W
#define NE   1024
#define ZSIZE 8388608      // 32*256*32*32
#define NSPLIT 4           // j-splits (256 codes each)
// 1-term fp16 (zh*eh): pairwise-diff sigma ~9e-3 -> 0.12 is ~13 sigma.
#define MARGIN 0.12f
#define ZPCAP 15360

// Output layout (floats): [loss(1)][z_q(ZSIZE)][perp(1)][idx(NVEC)][z_q1(ZSIZE)]
#define OUT_LOSS 0
#define OUT_ZQ   1
#define OUT_PERP 8388609
#define OUT_IDX  8388610
#define OUT_ZQ1  8421378

// Workspace layout (bytes)
#define WS_LOSS   0         // (unused legacy)
#define WS_RCNT   64
#define WS_GCNT   96
#define WS_MCNT   128       // 256 ints  -> 1152
#define WS_HIST   1152      // 1024 ints -> 5248
#define WS_ENORM  5248      // 1024 f    -> 9344 (pad 9472)
#define WS_IDX    9472      // 32768 ints -> 140544
#define WS_RLIST  140544    // 32768 ints -> 271616
#define WS_S1     271616    // 4*32768 f -> 795904
#define WS_S2     795904    // -> 1320192
#define WS_J1     1320192   // -> 1844480
#define WS_SCORE  1844480   // 32768 u64 -> 2106624
#define WS_EBH    2106624   // 1024*256 fp16 -> 2630912
#define WS_ZBH    2630912   // 32768*256 fp16 -> 19408128
#define WS_ZPACK  19408128  // 15360*256 f32 -> 35136768
#define WS_LPART  35136768  // 2048 f32 -> 35144960
#define WS_ZERO_INTS 1312   // bytes 0..5248: loss+rcnt+gcnt+mcnt+hist

typedef __attribute__((ext_vector_type(8))) short short8;
typedef __attribute__((ext_vector_type(4))) float f32x4;
typedef __attribute__((ext_vector_type(8))) unsigned short ushort8v;
typedef __attribute__((ext_vector_type(8))) _Float16 half8;

__device__ __forceinline__ unsigned short f16_rne(float x) {
    _Float16 h = (_Float16)x;
    return __builtin_bit_cast(unsigned short, h);
}
// CK-style block_sync_lds: drains LDS ops + barrier, leaves global loads (vmcnt) in flight.
__device__ __forceinline__ void lds_barrier() {
    asm volatile("s_waitcnt lgkmcnt(0)\n\ts_barrier" ::: "memory");
}
// Async global->LDS, 16B per lane. Dest is wave-uniform base; HW adds lane*16.
__device__ __forceinline__ void gload_lds16(const unsigned short* g, unsigned short* l) {
    __builtin_amdgcn_global_load_lds(
        (const __attribute__((address_space(1))) unsigned int*)g,
        (__attribute__((address_space(3))) unsigned int*)l, 16, 0, 0);
}

// ---------------- fused prep: z transpose+enc (blocks 0..511), emb enc+norm (512..527)
// Block 512 also zeroes loss/rcnt/gcnt/mcnt/hist.
__global__ __launch_bounds__(256) void vq_prep(
    const float* __restrict__ z, const float* __restrict__ emb,
    unsigned short* __restrict__ zbh, unsigned short* __restrict__ ebh,
    float* __restrict__ enorm, int* __restrict__ wsz)
{
    const int tid = threadIdx.x, w = tid >> 6, L = tid & 63;
    if (blockIdx.x < 512) {
        __shared__ unsigned short th[64 * 264];
        const int b = blockIdx.x >> 4, hw0 = (blockIdx.x & 15) << 6;
        const float* zp = z + (size_t)b * (CDIM * HW) + hw0;
        for (int i = 0; i < 16; ++i) {
            int k = (i * 4 + w) * 4;
            float f0 = zp[(size_t)(k + 0) * HW + L];
            float f1 = zp[(size_t)(k + 1) * HW + L];
            float f2 = zp[(size_t)(k + 2) * HW + L];
            float f3 = zp[(size_t)(k + 3) * HW + L];
            ushort4 hi = { f16_rne(f0), f16_rne(f1), f16_rne(f2), f16_rne(f3) };
            *(ushort4*)&th[L * 264 + k] = hi;
        }
        __syncthreads();
#pragma unroll
        for (int it = 0; it < 8; ++it) {
            int row = it * 8 + (tid >> 5);
            int kc = (tid & 31) * 8;
            size_t o = (size_t)(b * 1024 + hw0 + row) * CDIM + kc;
            *(ushort8v*)(zbh + o) = *(ushort8v*)&th[row * 264 + kc];
        }
    } else {
        if (blockIdx.x == 512) {
            for (int i = tid; i < WS_ZERO_INTS; i += 256) wsz[i] = 0;
        }
        const int cb = (int)(blockIdx.x - 512) * 64;
        for (int p = 0; p < 16; ++p) {
            int code = cb + p * 4 + w;
            float4 v = *(const float4*)(emb + (size_t)code * CDIM + L * 4);
            float s = v.x * v.x + v.y * v.y + v.z * v.z + v.w * v.w;
            for (int off = 32; off; off >>= 1) s += __shfl_down(s, off, 64);
            if (L == 0) enorm[code] = s;
            ushort4 hi = { f16_rne(v.x), f16_rne(v.y), f16_rne(v.z), f16_rne(v.w) };
            *(ushort4*)(ebh + (size_t)code * CDIM + L * 4) = hi;
        }
    }
}

// ---------------- 1-term fp16 MFMA GEMM, 32-code dbuf panels via global_load_lds
// r8 post-mortem: st[8] staging regs + AH(64) + acc(32) > 84-cap -> 13MB spill
// (WRITE_SIZE). v9: staging via global_load_lds (ZERO staging VGPRs, no
// ds_write); 32-code x K=256 panels double-buffered (2x16KB); 32 MFMAs/wave
// between barriers; launch_bounds(256,4) -> cap 128 VGPR, no spill, 4 blk/CU.
// Panel seg(jf,kk) content at shorts [seg*512 + L*8]: code jf*16+(L&15),
// k-chunk kk*32+(L>>4)*8 -- identical fragment layout to r6/r8 (verified).
// Wave w stages segs w*4+i (jf=w>>1, kk=(w&1)*4+i): dest = seg base (uniform)
// + lane*16B (HW), source per-lane = code row (jsbase+p*32+jf*16+r16).
__global__ __launch_bounds__(256, 4) void vq_mfma3(
    const unsigned short* __restrict__ zbh, const unsigned short* __restrict__ ebh,
    const float* __restrict__ enorm,
    float* __restrict__ s1_ws, float* __restrict__ s2_ws, int* __restrict__ j1_ws)
{
    __shared__ unsigned short bpan[2][8192];   // 2 x 16KB: 32-code K-panel
    __shared__ float en_s[256];

    const int tid = threadIdx.x, w = tid >> 6, L = tid & 63;
    const int l15 = L & 15, q = L >> 4;
    const int r16 = tid & 15;
    const int mtile = blockIdx.x & 255, js = blockIdx.x >> 8;   // js 0..3
    const int n0 = mtile << 7;
    const int jsbase = js << 8;

    // AH (z-high) in regs: 64 VGPRs
    half8 AH[2][8];
#pragma unroll
    for (int mf = 0; mf < 2; ++mf)
#pragma unroll
        for (int kk = 0; kk < 8; ++kk)
            AH[mf][kk] = *(const half8*)(zbh + (size_t)(n0 + w * 32 + mf * 16 + l15) * CDIM + kk * 32 + q * 8);

    en_s[tid] = enorm[jsbase + tid];

    float s1[2][4], s2[2][4]; int j1v[2][4];
#pragma unroll
    for (int mf = 0; mf < 2; ++mf)
#pragma unroll
        for (int r = 0; r < 4; ++r) { s1[mf][r] = -3.4e38f; s2[mf][r] = -3.4e38f; j1v[mf][r] = 0; }

    // staging source base for this thread: code row (jf_st*16 + r16), chunk (kk0)*32 + q*8
    const int jf_st = w >> 1;
    const int kk0 = (w & 1) * 4;
    const unsigned short* gsrc0 = ebh + (size_t)(jsbase + jf_st * 16 + r16) * CDIM + kk0 * 32 + q * 8;
    unsigned short* ldst0 = &bpan[0][(w * 4) * 512];
    unsigned short* ldst1 = &bpan[1][(w * 4) * 512];

#define ISSUE_PANEL(pp, ld)                                     \
    {                                                           \
        const unsigned short* gs = gsrc0 + (size_t)(pp) * 32 * CDIM; \
        gload_lds16(gs,      (ld));                             \
        gload_lds16(gs + 32, (ld) + 512);                       \
        gload_lds16(gs + 64, (ld) + 1024);                      \
        gload_lds16(gs + 96, (ld) + 1536);                      \
    }

    // prologue: panels 0,1 in flight; syncthreads drains vmcnt+lgkmcnt
    ISSUE_PANEL(0, ldst0);
    ISSUE_PANEL(1, ldst1);
    __syncthreads();

#pragma unroll 2
    for (int p = 0; p < 8; ++p) {
        const unsigned short* bb = bpan[p & 1];
        f32x4 acc[2][2] = {};
#pragma unroll
        for (int kk = 0; kk < 8; ++kk) {
#pragma unroll
            for (int jf = 0; jf < 2; ++jf) {
                half8 B = *(const half8*)(bb + (jf * 8 + kk) * 512 + L * 8);
                acc[0][jf] = __builtin_amdgcn_mfma_f32_16x16x32_f16(AH[0][kk], B, acc[0][jf], 0, 0, 0);
                acc[1][jf] = __builtin_amdgcn_mfma_f32_16x16x32_f16(AH[1][kk], B, acc[1][jf], 0, 0, 0);
            }
        }
        // fold scores for this panel's 32 codes
#pragma unroll
        for (int jf = 0; jf < 2; ++jf) {
            const int jl = p * 32 + jf * 16 + l15;
            const int j = jsbase + jl;
            const float hn = 0.5f * en_s[jl];
#pragma unroll
            for (int mf = 0; mf < 2; ++mf)
#pragma unroll
                for (int r = 0; r < 4; ++r) {
                    float s = acc[mf][jf][r] - hn;
                    if (s > s1[mf][r]) { s2[mf][r] = s1[mf][r]; s1[mf][r] = s; j1v[mf][r] = j; }
                    else if (s > s2[mf][r]) s2[mf][r] = s;
                }
        }
        __syncthreads();   // all waves done reading buf[p&1]; drains in-flight loads
        if (p < 6) {
            unsigned short* ld = (p & 1) ? ldst1 : ldst0;
            ISSUE_PANEL(p + 2, ld);
        }
    }
#undef ISSUE_PANEL

#pragma unroll
    for (int mf = 0; mf < 2; ++mf)
#pragma unroll
        for (int r = 0; r < 4; ++r) {
            float a1 = s1[mf][r], a2 = s2[mf][r]; int aj = j1v[mf][r];
            for (int m = 1; m < 16; m <<= 1) {
                float o1 = __shfl_xor(a1, m, 64);
                float o2 = __shfl_xor(a2, m, 64);
                int   oj = __shfl_xor(aj, m, 64);
                if (o1 > a1 || (o1 == a1 && oj < aj)) { a2 = fmaxf(a1, o2); a1 = o1; aj = oj; }
                else a2 = fmaxf(a2, o1);
            }
            if (l15 == 0) {
                int o = js * NVEC + n0 + w * 32 + mf * 16 + q * 4 + r;
                s1_ws[o] = a1; s2_ws[o] = a2; j1_ws[o] = aj;
            }
        }
}

// ---------------- merge 4 splits; confident rows -> outputs; rest -> rlist ----
__global__ __launch_bounds__(256) void vq_merge(
    const float* __restrict__ s1_ws, const float* __restrict__ s2_ws,
    const int* __restrict__ j1_ws, int* __restrict__ idx_ws,
    float* __restrict__ idx_out, int* __restrict__ hist,
    int* __restrict__ rcnt, int* __restrict__ rlist,
    unsigned long long* __restrict__ score)
{
    int n = blockIdx.x * 256 + threadIdx.x;
    score[n] = 0ull;
    float b1 = -3.4e38f, b2 = -3.4e38f; int bj = 0;
#pragma unroll
    for (int s = 0; s < NSPLIT; ++s) {
        float a1 = s1_ws[s * NVEC + n], a2 = s2_ws[s * NVEC + n];
        int aj = j1_ws[s * NVEC + n];
        if (a1 > b1 || (a1 == b1 && aj < bj)) { b2 = fmaxf(b1, a2); b1 = a1; bj = aj; }
        else b2 = fmaxf(b2, a1);
    }
    if (b1 - b2 < MARGIN) {
        idx_ws[n] = -1;
        int p = atomicAdd(rcnt, 1); rlist[p] = n;
    } else {
        idx_ws[n] = bj;
        idx_out[n] = (float)bj;
        atomicAdd(&hist[bj], 1);
    }
}

// ---------------- pack flagged z rows once -------------------------------------
__global__ __launch_bounds__(256) void vq_zpack(
    const float* __restrict__ z, const int* __restrict__ rcnt,
    const int* __restrict__ rlist, float* __restrict__ zpack)
{
    const int count = min(*rcnt, ZPCAP);
    for (int it = blockIdx.x; it < count; it += gridDim.x) {
        const int n = rlist[it];
        zpack[(size_t)it * 256 + threadIdx.x] =
            z[(size_t)(n >> 10) * (CDIM * HW) + (size_t)threadIdx.x * HW + (n & 1023)];
    }
}

// ---------------- exact fp32 rescore of flagged rows ---------------------------
__global__ __launch_bounds__(256) void vq_rescue(
    const float* __restrict__ z, const float* __restrict__ emb,
    const float* __restrict__ enorm, const int* __restrict__ rcnt,
    const int* __restrict__ rlist, const float* __restrict__ zpack,
    unsigned long long* __restrict__ score)
{
    __shared__ float en_s[64];
    __shared__ __align__(16) float zrow[256];
    __shared__ float rs[4];
    __shared__ int   rj[4];
    const int tid = threadIdx.x;
    const int wv = tid >> 6, L = tid & 63;
    const int chunk = blockIdx.x & 15;        // 16 chunks of 64 codes
    const int jwave = chunk * 64 + wv * 16;   // this wave's 16 codes
    const int jodd = L >> 5;                  // lo half-wave: even code, hi: odd
    const int rstride = gridDim.x >> 4;
    const int count = *rcnt;

    if (tid < 64) en_s[tid] = enorm[chunk * 64 + tid];
    __syncthreads();

    for (int it = blockIdx.x >> 4; it < count; it += rstride) {
        const int n = rlist[it];
        float4 zv;
        if (it < ZPCAP) {
            zv = *(const float4*)(zpack + (size_t)it * 256 + L * 4);
        } else {
            __syncthreads();
            zrow[tid] = z[(size_t)(n >> 10) * (CDIM * HW) + (size_t)tid * HW + (n & 1023)];
            __syncthreads();
            zv = *(const float4*)&zrow[L * 4];
        }

        float b1 = -3.4e38f; int bj = 0x7fffffff;
#pragma unroll
        for (int jo = 0; jo < 16; jo += 2) {
            const int jA = jwave + jo;
            const float4 eA = *(const float4*)(emb + (size_t)jA * CDIM + L * 4);
            const float4 eB = *(const float4*)(emb + (size_t)(jA + 1) * CDIM + L * 4);
            float pA = fmaf(zv.x, eA.x, fmaf(zv.y, eA.y, fmaf(zv.z, eA.z, zv.w * eA.w)));
            float pB = fmaf(zv.x, eB.x, fmaf(zv.y, eB.y, fmaf(zv.z, eB.z, zv.w * eB.w)));
            float tA = pA + __shfl_xor(pA, 32, 64);
            float tB = pB + __shfl_xor(pB, 32, 64);
            float u = (L < 32) ? tA : tB;
            u += __shfl_xor(u, 16, 64);
            u += __shfl_xor(u, 8, 64);
            u += __shfl_xor(u, 4, 64);
            u += __shfl_xor(u, 2, 64);
            u += __shfl_xor(u, 1, 64);
            const int j = jA + jodd;
            const float s = u - 0.5f * en_s[wv * 16 + jo + jodd];
            if (s > b1) { b1 = s; bj = j; }
        }
        {
            const float o1 = __shfl_xor(b1, 32, 64);
            const int   oj = __shfl_xor(bj, 32, 64);
            if (o1 > b1 || (o1 == b1 && oj < bj)) { b1 = o1; bj = oj; }
        }
        __syncthreads();
        if (L == 0) { rs[wv] = b1; rj[wv] = bj; }
        __syncthreads();
        if (tid == 0) {
            float f1 = rs[0]; int fj = rj[0];
#pragma unroll
            for (int v = 1; v < 4; ++v)
                if (rs[v] > f1 || (rs[v] == f1 && rj[v] < fj)) { f1 = rs[v]; fj = rj[v]; }
            unsigned key = __float_as_uint(f1);
            key = (key & 0x80000000u) ? ~key : (key | 0x80000000u);
            unsigned long long packed = ((unsigned long long)key << 32) | (unsigned)(~fj);
            atomicMax(&score[n], packed);
        }
    }
}

// ---------------- gather + outputs + per-block loss partial --------------------
__global__ __launch_bounds__(256) void vq_gather(
    const float* __restrict__ z, const float* __restrict__ emb,
    const int* __restrict__ idx_ws, const unsigned long long* __restrict__ score,
    float* __restrict__ zq, float* __restrict__ zq1,
    float* __restrict__ idx_out, int* __restrict__ hist,
    float* __restrict__ loss_part)
{
    __shared__ float es[32 * 129];
    __shared__ int ids[32];
    __shared__ float wred[4];

    const int tid = threadIdx.x, w = tid >> 6, L = tid & 63;
    const int b   = blockIdx.x >> 6;
    const int half = (blockIdx.x >> 5) & 1;
    const int hw0 = (blockIdx.x & 31) << 5;
    const int n0  = (b << 10) + hw0;
    const int c0  = half << 7;

    if (tid < 32) {
        const int n = n0 + tid;
        int id = idx_ws[n];
        if (id < 0) {
            id = (int)(~(unsigned)score[n]) & (NE - 1);
            if (half == 0) {            // exactly-once fixup for flagged rows
                idx_out[n] = (float)id;
                atomicAdd(&hist[id], 1);
            }
        }
        ids[tid] = id;
    }
    __syncthreads();

#pragma unroll
    for (int p = 0; p < 4; ++p) {
        int u = p * 256 + tid;
        int r = u >> 5, cq = (u & 31) * 4;
        float4 v = *(const float4*)(emb + (size_t)ids[r] * CDIM + c0 + cq);
        es[r * 129 + cq + 0] = v.x;
        es[r * 129 + cq + 1] = v.y;
        es[r * 129 + cq + 2] = v.z;
        es[r * 129 + cq + 3] = v.w;
    }
    __syncthreads();

    const int row = L & 31, cp = L >> 5;
    const size_t zbase = (size_t)b * (CDIM * HW) + hw0 + row;
    float ls = 0.f;
    for (int rd = 0; rd < 16; ++rd) {
        int cl = rd * 8 + w * 2 + cp;
        size_t off = zbase + (size_t)(c0 + cl) * HW;
        float zv = z[off];
        float e  = es[row * 129 + cl];
        float d  = e - zv;
        zq[off]  = zv + d;     // match ref: zp + (z_q1 - zp)
        zq1[off] = e;
        ls += d * d;
    }

    for (int off = 32; off; off >>= 1) ls += __shfl_down(ls, off, 64);
    if (L == 0) wred[w] = ls;
    __syncthreads();
    if (tid == 0)
        loss_part[blockIdx.x] = wred[0] + wred[1] + wred[2] + wred[3];
}

// ---------------- finalize: loss scalar + perplexity ---------------------------
__global__ __launch_bounds__(1024) void vq_final(
    const int* __restrict__ hist, const float* __restrict__ loss_part,
    float* __restrict__ out_loss, float* __restrict__ out_perp)
{
    int tid = threadIdx.x;
    float em = (float)hist[tid] * (1.0f / 32768.0f);
    float term = em * logf(em + 1e-10f);
    double dl = (double)loss_part[tid] + (double)loss_part[tid + 1024];
    for (int off = 32; off; off >>= 1) {
        term += __shfl_down(term, off, 64);
        dl   += __shfl_down(dl, off, 64);
    }
    __shared__ float red[16];
    __shared__ double redd[16];
    int lane = tid & 63, wv = tid >> 6;
    if (lane == 0) { red[wv] = term; redd[wv] = dl; }
    __syncthreads();
    if (tid == 0) {
        float s = 0.f; double dsum = 0.0;
        for (int i = 0; i < 16; ++i) { s += red[i]; dsum += redd[i]; }
        *out_perp = expf(-s);
        *out_loss = (float)(dsum * 1.25 / 8388608.0);
    }
}

extern "C" void kernel_launch(void* const* d_in, const int* in_sizes, int n_in,
                              void* d_out, int out_size, void* d_ws, size_t ws_size,
                              hipStream_t stream) {
    const float* z   = (const float*)d_in[0];
    const float* emb = (const float*)d_in[1];
    float* out = (float*)d_out;
    char*  ws  = (char*)d_ws;

    int*    rcnt        = (int*)(ws + WS_RCNT);
    int*    hist        = (int*)(ws + WS_HIST);
    float*  enorm       = (float*)(ws + WS_ENORM);
    int*    idx_ws      = (int*)(ws + WS_IDX);
    int*    rlist       = (int*)(ws + WS_RLIST);
    float*  s1_ws       = (float*)(ws + WS_S1);
    float*  s2_ws       = (float*)(ws + WS_S2);
    int*    j1_ws       = (int*)(ws + WS_J1);
    unsigned short* ebh = (unsigned short*)(ws + WS_EBH);
    unsigned short* zbh = (unsigned short*)(ws + WS_ZBH);
    float*  zpack       = (float*)(ws + WS_ZPACK);
    float*  loss_part   = (float*)(ws + WS_LPART);
    unsigned long long* score = (unsigned long long*)(ws + WS_SCORE);

    vq_prep  <<<528, 256, 0, stream>>>(z, emb, zbh, ebh, enorm, (int*)ws);
    vq_mfma3 <<<1024, 256, 0, stream>>>(zbh, ebh, enorm, s1_ws, s2_ws, j1_ws);
    vq_merge <<<128, 256, 0, stream>>>(s1_ws, s2_ws, j1_ws, idx_ws, out + OUT_IDX, hist, rcnt, rlist, score);
    vq_zpack <<<1024, 256, 0, stream>>>(z, rcnt, rlist, zpack);
    vq_rescue<<<2048, 256, 0, stream>>>(z, emb, enorm, rcnt, rlist, zpack, score);
    vq_gather<<<2048, 256, 0, stream>>>(z, emb, idx_ws, score, out + OUT_ZQ, out + OUT_ZQ1,
                                        out + OUT_IDX, hist, loss_part);
    vq_final <<<1, 1024, 0, stream>>>(hist, loss_part, out + OUT_LOSS, out + OUT_PERP);
}

// Round 10
// 225.468 us; speedup vs baseline: 1.6367x; 1.0183x over previous
//
#include <hip/hip_runtime.h>
#include <hip/hip_bf16.h>
#include <math.h>

// Problem constants
#define CDIM 256
#define HW   1024          // 32*32
#define NVEC 32768         // B*H*W
#define NE   1024
#define ZSIZE 8388608      // 32*256*32*32
#define NSPLIT 4           // j-splits (256 codes each)
// 1-term fp16 (zh*eh): pairwise-diff sigma ~9e-3 -> 0.12 is ~13 sigma.
#define MARGIN 0.12f
#define ZPCAP 15360

// Output layout (floats): [loss(1)][z_q(ZSIZE)][perp(1)][idx(NVEC)][z_q1(ZSIZE)]
#define OUT_LOSS 0
#define OUT_ZQ   1
#define OUT_PERP 8388609
#define OUT_IDX  8388610
#define OUT_ZQ1  8421378

// Workspace layout (bytes)
#define WS_LOSS   0         // (unused legacy)
#define WS_RCNT   64
#define WS_GCNT   96
#define WS_MCNT   128       // 256 ints  -> 1152
#define WS_HIST   1152      // 1024 ints -> 5248
#define WS_ENORM  5248      // 1024 f    -> 9344 (pad 9472)
#define WS_IDX    9472      // 32768 ints -> 140544
#define WS_RLIST  140544    // 32768 ints -> 271616
#define WS_S1     271616    // 4*32768 f -> 795904
#define WS_S2     795904    // -> 1320192
#define WS_J1     1320192   // -> 1844480
#define WS_SCORE  1844480   // 32768 u64 -> 2106624
#define WS_EBH    2106624   // 1024*256 fp16 -> 2630912
#define WS_ZBH    2630912   // 32768*256 fp16 -> 19408128
#define WS_ZPACK  19408128  // 15360*256 f32 -> 35136768
#define WS_LPART  35136768  // 2048 f32 -> 35144960
#define WS_ZERO_INTS 1312   // bytes 0..5248: loss+rcnt+gcnt+mcnt+hist

typedef __attribute__((ext_vector_type(8))) short short8;
typedef __attribute__((ext_vector_type(4))) float f32x4;
typedef __attribute__((ext_vector_type(8))) unsigned short ushort8v;
typedef __attribute__((ext_vector_type(8))) _Float16 half8;

__device__ __forceinline__ unsigned short f16_rne(float x) {
    _Float16 h = (_Float16)x;
    return __builtin_bit_cast(unsigned short, h);
}
// CK-style block_sync_lds: drains LDS ops + barrier, leaves global loads (vmcnt) in flight.
__device__ __forceinline__ void lds_barrier() {
    asm volatile("s_waitcnt lgkmcnt(0)\n\ts_barrier" ::: "memory");
}
// Async global->LDS, 16B per lane. Dest is wave-uniform base; HW adds lane*16.
__device__ __forceinline__ void gload_lds16(const unsigned short* g, unsigned short* l) {
    __builtin_amdgcn_global_load_lds(
        (const __attribute__((address_space(1))) unsigned int*)g,
        (__attribute__((address_space(3))) unsigned int*)l, 16, 0, 0);
}

// ---------------- fused prep: z transpose+enc (blocks 0..511), emb enc+norm (512..527)
// Block 512 also zeroes loss/rcnt/gcnt/mcnt/hist.
__global__ __launch_bounds__(256) void vq_prep(
    const float* __restrict__ z, const float* __restrict__ emb,
    unsigned short* __restrict__ zbh, unsigned short* __restrict__ ebh,
    float* __restrict__ enorm, int* __restrict__ wsz)
{
    const int tid = threadIdx.x, w = tid >> 6, L = tid & 63;
    if (blockIdx.x < 512) {
        __shared__ unsigned short th[64 * 264];
        const int b = blockIdx.x >> 4, hw0 = (blockIdx.x & 15) << 6;
        const float* zp = z + (size_t)b * (CDIM * HW) + hw0;
        for (int i = 0; i < 16; ++i) {
            int k = (i * 4 + w) * 4;
            float f0 = zp[(size_t)(k + 0) * HW + L];
            float f1 = zp[(size_t)(k + 1) * HW + L];
            float f2 = zp[(size_t)(k + 2) * HW + L];
            float f3 = zp[(size_t)(k + 3) * HW + L];
            ushort4 hi = { f16_rne(f0), f16_rne(f1), f16_rne(f2), f16_rne(f3) };
            *(ushort4*)&th[L * 264 + k] = hi;
        }
        __syncthreads();
#pragma unroll
        for (int it = 0; it < 8; ++it) {
            int row = it * 8 + (tid >> 5);
            int kc = (tid & 31) * 8;
            size_t o = (size_t)(b * 1024 + hw0 + row) * CDIM + kc;
            *(ushort8v*)(zbh + o) = *(ushort8v*)&th[row * 264 + kc];
        }
    } else {
        if (blockIdx.x == 512) {
            for (int i = tid; i < WS_ZERO_INTS; i += 256) wsz[i] = 0;
        }
        const int cb = (int)(blockIdx.x - 512) * 64;
        for (int p = 0; p < 16; ++p) {
            int code = cb + p * 4 + w;
            float4 v = *(const float4*)(emb + (size_t)code * CDIM + L * 4);
            float s = v.x * v.x + v.y * v.y + v.z * v.z + v.w * v.w;
            for (int off = 32; off; off >>= 1) s += __shfl_down(s, off, 64);
            if (L == 0) enorm[code] = s;
            ushort4 hi = { f16_rne(v.x), f16_rne(v.y), f16_rne(v.z), f16_rne(v.w) };
            *(ushort4*)(ebh + (size_t)code * CDIM + L * 4) = hi;
        }
    }
}

// ---------------- 1-term fp16 MFMA GEMM, 32-code dbuf panels via global_load_lds
// r9 post-mortem: launch_bounds(256,4) made the allocator pin to the 64-reg
// occupancy tier and spill AH (WRITE_SIZE 9.7MB vs 1.6MB legit). v10: bounds
// (256,2) -> 256-reg tier; AH(64)+acc(16)+trackers(24) fit with slack, zero
// scratch. 2 blocks/CU (8 waves); 8 barriers; 32 MFMAs/wave between barriers;
// staging via global_load_lds (zero staging VGPRs).
__global__ __launch_bounds__(256, 2) void vq_mfma3(
    const unsigned short* __restrict__ zbh, const unsigned short* __restrict__ ebh,
    const float* __restrict__ enorm,
    float* __restrict__ s1_ws, float* __restrict__ s2_ws, int* __restrict__ j1_ws)
{
    __shared__ unsigned short bpan[2][8192];   // 2 x 16KB: 32-code K-panel
    __shared__ float en_s[256];

    const int tid = threadIdx.x, w = tid >> 6, L = tid & 63;
    const int l15 = L & 15, q = L >> 4;
    const int r16 = tid & 15;
    const int mtile = blockIdx.x & 255, js = blockIdx.x >> 8;   // js 0..3
    const int n0 = mtile << 7;
    const int jsbase = js << 8;

    // AH (z-high) in regs: 64 VGPRs
    half8 AH[2][8];
#pragma unroll
    for (int mf = 0; mf < 2; ++mf)
#pragma unroll
        for (int kk = 0; kk < 8; ++kk)
            AH[mf][kk] = *(const half8*)(zbh + (size_t)(n0 + w * 32 + mf * 16 + l15) * CDIM + kk * 32 + q * 8);

    en_s[tid] = enorm[jsbase + tid];

    float s1[2][4], s2[2][4]; int j1v[2][4];
#pragma unroll
    for (int mf = 0; mf < 2; ++mf)
#pragma unroll
        for (int r = 0; r < 4; ++r) { s1[mf][r] = -3.4e38f; s2[mf][r] = -3.4e38f; j1v[mf][r] = 0; }

    // staging source base for this thread: code row (jf_st*16 + r16), chunk (kk0)*32 + q*8
    const int jf_st = w >> 1;
    const int kk0 = (w & 1) * 4;
    const unsigned short* gsrc0 = ebh + (size_t)(jsbase + jf_st * 16 + r16) * CDIM + kk0 * 32 + q * 8;
    unsigned short* ldst0 = &bpan[0][(w * 4) * 512];
    unsigned short* ldst1 = &bpan[1][(w * 4) * 512];

#define ISSUE_PANEL(pp, ld)                                     \
    {                                                           \
        const unsigned short* gs = gsrc0 + (size_t)(pp) * 32 * CDIM; \
        gload_lds16(gs,      (ld));                             \
        gload_lds16(gs + 32, (ld) + 512);                       \
        gload_lds16(gs + 64, (ld) + 1024);                      \
        gload_lds16(gs + 96, (ld) + 1536);                      \
    }

    // prologue: panels 0,1 in flight; syncthreads drains vmcnt+lgkmcnt
    ISSUE_PANEL(0, ldst0);
    ISSUE_PANEL(1, ldst1);
    __syncthreads();

#pragma unroll 2
    for (int p = 0; p < 8; ++p) {
        const unsigned short* bb = bpan[p & 1];
        f32x4 acc[2][2] = {};
#pragma unroll
        for (int kk = 0; kk < 8; ++kk) {
#pragma unroll
            for (int jf = 0; jf < 2; ++jf) {
                half8 B = *(const half8*)(bb + (jf * 8 + kk) * 512 + L * 8);
                acc[0][jf] = __builtin_amdgcn_mfma_f32_16x16x32_f16(AH[0][kk], B, acc[0][jf], 0, 0, 0);
                acc[1][jf] = __builtin_amdgcn_mfma_f32_16x16x32_f16(AH[1][kk], B, acc[1][jf], 0, 0, 0);
            }
        }
        // fold scores for this panel's 32 codes
#pragma unroll
        for (int jf = 0; jf < 2; ++jf) {
            const int jl = p * 32 + jf * 16 + l15;
            const int j = jsbase + jl;
            const float hn = 0.5f * en_s[jl];
#pragma unroll
            for (int mf = 0; mf < 2; ++mf)
#pragma unroll
                for (int r = 0; r < 4; ++r) {
                    float s = acc[mf][jf][r] - hn;
                    if (s > s1[mf][r]) { s2[mf][r] = s1[mf][r]; s1[mf][r] = s; j1v[mf][r] = j; }
                    else if (s > s2[mf][r]) s2[mf][r] = s;
                }
        }
        __syncthreads();   // all waves done reading buf[p&1]; drains in-flight loads
        if (p < 6) {
            unsigned short* ld = (p & 1) ? ldst1 : ldst0;
            ISSUE_PANEL(p + 2, ld);
        }
    }
#undef ISSUE_PANEL

#pragma unroll
    for (int mf = 0; mf < 2; ++mf)
#pragma unroll
        for (int r = 0; r < 4; ++r) {
            float a1 = s1[mf][r], a2 = s2[mf][r]; int aj = j1v[mf][r];
            for (int m = 1; m < 16; m <<= 1) {
                float o1 = __shfl_xor(a1, m, 64);
                float o2 = __shfl_xor(a2, m, 64);
                int   oj = __shfl_xor(aj, m, 64);
                if (o1 > a1 || (o1 == a1 && oj < aj)) { a2 = fmaxf(a1, o2); a1 = o1; aj = oj; }
                else a2 = fmaxf(a2, o1);
            }
            if (l15 == 0) {
                int o = js * NVEC + n0 + w * 32 + mf * 16 + q * 4 + r;
                s1_ws[o] = a1; s2_ws[o] = a2; j1_ws[o] = aj;
            }
        }
}

// ---------------- merge 4 splits + pack flagged z rows (zpack fused) -----------
// A merge block knows each row it flags AND its rlist position (atomicAdd
// return), so it packs those z-rows itself -- no cross-block dependency, no
// fences (r7's failure was threadfence/single-address atomics, not packing).
__global__ __launch_bounds__(256) void vq_merge(
    const float* __restrict__ s1_ws, const float* __restrict__ s2_ws,
    const int* __restrict__ j1_ws, const float* __restrict__ z,
    int* __restrict__ idx_ws, float* __restrict__ idx_out, int* __restrict__ hist,
    int* __restrict__ rcnt, int* __restrict__ rlist,
    unsigned long long* __restrict__ score, float* __restrict__ zpack)
{
    __shared__ int sh_n[256];
    __shared__ int sh_p[256];
    __shared__ int sh_cnt;
    const int tid = threadIdx.x;
    if (tid == 0) sh_cnt = 0;
    __syncthreads();

    int n = blockIdx.x * 256 + tid;
    score[n] = 0ull;
    float b1 = -3.4e38f, b2 = -3.4e38f; int bj = 0;
#pragma unroll
    for (int s = 0; s < NSPLIT; ++s) {
        float a1 = s1_ws[s * NVEC + n], a2 = s2_ws[s * NVEC + n];
        int aj = j1_ws[s * NVEC + n];
        if (a1 > b1 || (a1 == b1 && aj < bj)) { b2 = fmaxf(b1, a2); b1 = a1; bj = aj; }
        else b2 = fmaxf(b2, a1);
    }
    if (b1 - b2 < MARGIN) {
        idx_ws[n] = -1;
        int p = atomicAdd(rcnt, 1); rlist[p] = n;
        int c = atomicAdd(&sh_cnt, 1); sh_n[c] = n; sh_p[c] = p;
    } else {
        idx_ws[n] = bj;
        idx_out[n] = (float)bj;
        atomicAdd(&hist[bj], 1);
    }
    __syncthreads();
    const int fc = sh_cnt;
    for (int i = 0; i < fc; ++i) {
        const int fn = sh_n[i], fp = sh_p[i];
        if (fp < ZPCAP)
            zpack[(size_t)fp * 256 + tid] =
                z[(size_t)(fn >> 10) * (CDIM * HW) + (size_t)tid * HW + (fn & 1023)];
    }
}

// ---------------- exact fp32 rescore of flagged rows ---------------------------
__global__ __launch_bounds__(256) void vq_rescue(
    const float* __restrict__ z, const float* __restrict__ emb,
    const float* __restrict__ enorm, const int* __restrict__ rcnt,
    const int* __restrict__ rlist, const float* __restrict__ zpack,
    unsigned long long* __restrict__ score)
{
    __shared__ float en_s[64];
    __shared__ __align__(16) float zrow[256];
    __shared__ float rs[4];
    __shared__ int   rj[4];
    const int tid = threadIdx.x;
    const int wv = tid >> 6, L = tid & 63;
    const int chunk = blockIdx.x & 15;        // 16 chunks of 64 codes
    const int jwave = chunk * 64 + wv * 16;   // this wave's 16 codes
    const int jodd = L >> 5;                  // lo half-wave: even code, hi: odd
    const int rstride = gridDim.x >> 4;
    const int count = *rcnt;

    if (tid < 64) en_s[tid] = enorm[chunk * 64 + tid];
    __syncthreads();

    for (int it = blockIdx.x >> 4; it < count; it += rstride) {
        const int n = rlist[it];
        float4 zv;
        if (it < ZPCAP) {
            zv = *(const float4*)(zpack + (size_t)it * 256 + L * 4);
        } else {
            __syncthreads();
            zrow[tid] = z[(size_t)(n >> 10) * (CDIM * HW) + (size_t)tid * HW + (n & 1023)];
            __syncthreads();
            zv = *(const float4*)&zrow[L * 4];
        }

        float b1 = -3.4e38f; int bj = 0x7fffffff;
#pragma unroll
        for (int jo = 0; jo < 16; jo += 2) {
            const int jA = jwave + jo;
            const float4 eA = *(const float4*)(emb + (size_t)jA * CDIM + L * 4);
            const float4 eB = *(const float4*)(emb + (size_t)(jA + 1) * CDIM + L * 4);
            float pA = fmaf(zv.x, eA.x, fmaf(zv.y, eA.y, fmaf(zv.z, eA.z, zv.w * eA.w)));
            float pB = fmaf(zv.x, eB.x, fmaf(zv.y, eB.y, fmaf(zv.z, eB.z, zv.w * eB.w)));
            float tA = pA + __shfl_xor(pA, 32, 64);
            float tB = pB + __shfl_xor(pB, 32, 64);
            float u = (L < 32) ? tA : tB;
            u += __shfl_xor(u, 16, 64);
            u += __shfl_xor(u, 8, 64);
            u += __shfl_xor(u, 4, 64);
            u += __shfl_xor(u, 2, 64);
            u += __shfl_xor(u, 1, 64);
            const int j = jA + jodd;
            const float s = u - 0.5f * en_s[wv * 16 + jo + jodd];
            if (s > b1) { b1 = s; bj = j; }
        }
        {
            const float o1 = __shfl_xor(b1, 32, 64);
            const int   oj = __shfl_xor(bj, 32, 64);
            if (o1 > b1 || (o1 == b1 && oj < bj)) { b1 = o1; bj = oj; }
        }
        __syncthreads();
        if (L == 0) { rs[wv] = b1; rj[wv] = bj; }
        __syncthreads();
        if (tid == 0) {
            float f1 = rs[0]; int fj = rj[0];
#pragma unroll
            for (int v = 1; v < 4; ++v)
                if (rs[v] > f1 || (rs[v] == f1 && rj[v] < fj)) { f1 = rs[v]; fj = rj[v]; }
            unsigned key = __float_as_uint(f1);
            key = (key & 0x80000000u) ? ~key : (key | 0x80000000u);
            unsigned long long packed = ((unsigned long long)key << 32) | (unsigned)(~fj);
            atomicMax(&score[n], packed);
        }
    }
}

// ---------------- gather + outputs + per-block loss partial --------------------
__global__ __launch_bounds__(256) void vq_gather(
    const float* __restrict__ z, const float* __restrict__ emb,
    const int* __restrict__ idx_ws, const unsigned long long* __restrict__ score,
    float* __restrict__ zq, float* __restrict__ zq1,
    float* __restrict__ idx_out, int* __restrict__ hist,
    float* __restrict__ loss_part)
{
    __shared__ float es[32 * 129];
    __shared__ int ids[32];
    __shared__ float wred[4];

    const int tid = threadIdx.x, w = tid >> 6, L = tid & 63;
    const int b   = blockIdx.x >> 6;
    const int half = (blockIdx.x >> 5) & 1;
    const int hw0 = (blockIdx.x & 31) << 5;
    const int n0  = (b << 10) + hw0;
    const int c0  = half << 7;

    if (tid < 32) {
        const int n = n0 + tid;
        int id = idx_ws[n];
        if (id < 0) {
            id = (int)(~(unsigned)score[n]) & (NE - 1);
            if (half == 0) {            // exactly-once fixup for flagged rows
                idx_out[n] = (float)id;
                atomicAdd(&hist[id], 1);
            }
        }
        ids[tid] = id;
    }
    __syncthreads();

#pragma unroll
    for (int p = 0; p < 4; ++p) {
        int u = p * 256 + tid;
        int r = u >> 5, cq = (u & 31) * 4;
        float4 v = *(const float4*)(emb + (size_t)ids[r] * CDIM + c0 + cq);
        es[r * 129 + cq + 0] = v.x;
        es[r * 129 + cq + 1] = v.y;
        es[r * 129 + cq + 2] = v.z;
        es[r * 129 + cq + 3] = v.w;
    }
    __syncthreads();

    const int row = L & 31, cp = L >> 5;
    const size_t zbase = (size_t)b * (CDIM * HW) + hw0 + row;
    float ls = 0.f;
    for (int rd = 0; rd < 16; ++rd) {
        int cl = rd * 8 + w * 2 + cp;
        size_t off = zbase + (size_t)(c0 + cl) * HW;
        float zv = z[off];
        float e  = es[row * 129 + cl];
        float d  = e - zv;
        zq[off]  = zv + d;     // match ref: zp + (z_q1 - zp)
        zq1[off] = e;
        ls += d * d;
    }

    for (int off = 32; off; off >>= 1) ls += __shfl_down(ls, off, 64);
    if (L == 0) wred[w] = ls;
    __syncthreads();
    if (tid == 0)
        loss_part[blockIdx.x] = wred[0] + wred[1] + wred[2] + wred[3];
}

// ---------------- finalize: loss scalar + perplexity ---------------------------
__global__ __launch_bounds__(1024) void vq_final(
    const int* __restrict__ hist, const float* __restrict__ loss_part,
    float* __restrict__ out_loss, float* __restrict__ out_perp)
{
    int tid = threadIdx.x;
    float em = (float)hist[tid] * (1.0f / 32768.0f);
    float term = em * logf(em + 1e-10f);
    double dl = (double)loss_part[tid] + (double)loss_part[tid + 1024];
    for (int off = 32; off; off >>= 1) {
        term += __shfl_down(term, off, 64);
        dl   += __shfl_down(dl, off, 64);
    }
    __shared__ float red[16];
    __shared__ double redd[16];
    int lane = tid & 63, wv = tid >> 6;
    if (lane == 0) { red[wv] = term; redd[wv] = dl; }
    __syncthreads();
    if (tid == 0) {
        float s = 0.f; double dsum = 0.0;
        for (int i = 0; i < 16; ++i) { s += red[i]; dsum += redd[i]; }
        *out_perp = expf(-s);
        *out_loss = (float)(dsum * 1.25 / 8388608.0);
    }
}

extern "C" void kernel_launch(void* const* d_in, const int* in_sizes, int n_in,
                              void* d_out, int out_size, void* d_ws, size_t ws_size,
                              hipStream_t stream) {
    const float* z   = (const float*)d_in[0];
    const float* emb = (const float*)d_in[1];
    float* out = (float*)d_out;
    char*  ws  = (char*)d_ws;

    int*    rcnt        = (int*)(ws + WS_RCNT);
    int*    hist        = (int*)(ws + WS_HIST);
    float*  enorm       = (float*)(ws + WS_ENORM);
    int*    idx_ws      = (int*)(ws + WS_IDX);
    int*    rlist       = (int*)(ws + WS_RLIST);
    float*  s1_ws       = (float*)(ws + WS_S1);
    float*  s2_ws       = (float*)(ws + WS_S2);
    int*    j1_ws       = (int*)(ws + WS_J1);
    unsigned short* ebh = (unsigned short*)(ws + WS_EBH);
    unsigned short* zbh = (unsigned short*)(ws + WS_ZBH);
    float*  zpack       = (float*)(ws + WS_ZPACK);
    float*  loss_part   = (float*)(ws + WS_LPART);
    unsigned long long* score = (unsigned long long*)(ws + WS_SCORE);

    vq_prep  <<<528, 256, 0, stream>>>(z, emb, zbh, ebh, enorm, (int*)ws);
    vq_mfma3 <<<1024, 256, 0, stream>>>(zbh, ebh, enorm, s1_ws, s2_ws, j1_ws);
    vq_merge <<<128, 256, 0, stream>>>(s1_ws, s2_ws, j1_ws, z, idx_ws, out + OUT_IDX,
                                       hist, rcnt, rlist, score, zpack);
    vq_rescue<<<2048, 256, 0, stream>>>(z, emb, enorm, rcnt, rlist, zpack, score);
    vq_gather<<<2048, 256, 0, stream>>>(z, emb, idx_ws, score, out + OUT_ZQ, out + OUT_ZQ1,
                                        out + OUT_IDX, hist, loss_part);
    vq_final <<<1, 1024, 0, stream>>>(hist, loss_part, out + OUT_LOSS, out + OUT_PERP);
}